// Round 2
// baseline (550.082 us; speedup 1.0000x reference)
//
#include <hip/hip_runtime.h>

typedef float v4f __attribute__((ext_vector_type(4)));
typedef short v8s __attribute__((ext_vector_type(8)));
typedef unsigned v4u __attribute__((ext_vector_type(4)));

#define NSLOT 8
#define OUTN 57344  // 128*448

__device__ __forceinline__ unsigned short f2bf_rn(float f) {
  unsigned u = __float_as_uint(f);
  return (unsigned short)((u + 0x7fffu + ((u >> 16) & 1u)) >> 16);
}

__device__ __forceinline__ float gelu_phi(float x) {
  float t = tanhf(0.7978845608f * (x + 0.044715f * x * x * x));
  return 0.5f * x * (1.0f + t) * 1.5338375f;  // /PHI_C
}

// ---------------- MLP ----------------
__global__ __launch_bounds__(256) void k_mlp1(const float* __restrict__ emb, const float* __restrict__ W0,
                                              float* __restrict__ act1)
{
  const int b = blockIdx.x, j = threadIdx.x;
  float s = 0.f;
#pragma unroll 8
  for (int x = 0; x < 64; ++x) s += emb[b * 64 + x] * W0[x * 256 + j];
  act1[b * 256 + j] = gelu_phi(s * 0.125f);
}

__global__ __launch_bounds__(256) void k_mlp2(const float* __restrict__ act1, const float* __restrict__ W1,
                                              float* __restrict__ act2)
{
  const int b = blockIdx.x, j = threadIdx.x;
  float s = 0.f;
#pragma unroll 16
  for (int x = 0; x < 256; ++x) s += act1[b * 256 + x] * W1[x * 256 + j];
  act2[b * 256 + j] = gelu_phi(s * 0.0625f);
}

__global__ __launch_bounds__(256) void k_mlp3(const float* __restrict__ act2, const float* __restrict__ W2,
                                              float* __restrict__ hsT)
{
  const int o = blockIdx.x * 256 + threadIdx.x;
  const int b = o >> 6, e = o & 63;
  float s = 0.f;
#pragma unroll 16
  for (int x = 0; x < 256; ++x) s += act2[b * 256 + x] * W2[x * 64 + e];
  hsT[e * 128 + b] = gelu_phi(s * 0.0625f) * 0.125f;  // hs * 64^-0.5, transposed [x][b]
}

// ---------------- build A matrices (bf16) ----------------
// A1[b][x*64+u]       = bf16(hs[b][x] * s1[b][u])          (128 x 4096)
// A2[g*128+b][x*64+u] = bf16(hs[b][x] * v1[b][u][g])       (384 x 4096)
__global__ __launch_bounds__(256) void k_prepA(const float* __restrict__ x1, const float* __restrict__ hsT,
                                               unsigned short* __restrict__ A1, unsigned short* __restrict__ A2)
{
  const int row = blockIdx.x;  // 0..511
  const int tid = threadIdx.x;
  const int x = tid >> 2, u0 = (tid & 3) << 4;
  const int b = row & 127;
  const float hv = hsT[x * 128 + b];
  unsigned short tmp[16];
  unsigned short* dst;
  if (row < 128) {
#pragma unroll
    for (int uu = 0; uu < 16; ++uu) tmp[uu] = f2bf_rn(hv * x1[b * 256 + u0 + uu]);
    dst = A1 + (size_t)row * 4096;
  } else {
    const int g = (row - 128) >> 7;
#pragma unroll
    for (int uu = 0; uu < 16; ++uu) tmp[uu] = f2bf_rn(hv * x1[b * 256 + 64 + (u0 + uu) * 3 + g]);
    dst = A2 + (size_t)(row - 128) * 4096;
  }
  v8s* o = (v8s*)(dst + x * 64 + u0);
  o[0] = *(v8s*)&tmp[0];
  o[1] = *(v8s*)&tmp[8];
}

// ---------------- fused GEMM + epilogue ----------------
// grid = 5 slices * 64 v * 4 ksplit = 1280 blocks.
// Block: M = 128 (slices 0,1 / A1) or 384 (slices 2..4 / A2), N = 64 (one v), K-chunk = 1024.
// B-tile (32k x 64n fp32 of P) staged via LDS as [kpair][n] dwords (stride 68: b128 writes hit
// bank-quads uniformly -> floor rate; b32 frag reads <=2-way). A-frags loaded directly (L2-hot bf16).
// Register prefetch of next B-tile spans the barrier pair.
__global__ __launch_bounds__(256, 3) void gemm_k(
    const float* __restrict__ P0, const float* __restrict__ P1, const float* __restrict__ P2,
    const float* __restrict__ P3, const float* __restrict__ P4,
    const unsigned short* __restrict__ A1, const unsigned short* __restrict__ A2,
    const float* __restrict__ x2, float* __restrict__ out_acc)
{
  __shared__ unsigned ldsB[16 * 68];
  __shared__ float wS[128];
  __shared__ float wV[128][3];

  const int tid = threadIdx.x;
  const int bid = blockIdx.x;
  const int slice = bid >> 8;          // 0..4
  const int v = (bid >> 2) & 63;
  const int ks = bid & 3;
  const float* __restrict__ P = (slice == 0) ? P0 : (slice == 1) ? P1 : (slice == 2) ? P2 : (slice == 3) ? P3 : P4;
  const unsigned short* __restrict__ A = (slice < 2) ? A1 : A2;
  const int nmt = (slice < 2) ? 2 : 6;  // mtiles per wave

  if (tid < 128) {
    wS[tid] = x2[tid * 256 + v];
    wV[tid][0] = x2[tid * 256 + 64 + v * 3 + 0];
    wV[tid][1] = x2[tid * 256 + 64 + v * 3 + 1];
    wV[tid][2] = x2[tid * 256 + 64 + v * 3 + 2];
  }

  const int lane = tid & 63, wav = tid >> 6;
  const int l16 = lane & 15, quad = lane >> 4;
  const int tq = tid & 15, kp = tid >> 4;

  // A byte-offsets per mtile (row fixed per lane)
  int aoff[6];
#pragma unroll
  for (int t = 0; t < 6; ++t)
    aoff[t] = ((16 * (wav + 4 * t) + l16) * 4096 + quad * 8) * 2;

  v4f acc[6][4];
#pragma unroll
  for (int t = 0; t < 6; ++t)
#pragma unroll
    for (int nf = 0; nf < 4; ++nf) acc[t][nf] = (v4f){0.f, 0.f, 0.f, 0.f};

  const float* src0 = P + (size_t)(ks * 1024 + 2 * kp) * 4096 + v * 64 + 4 * tq;
  float4 pr0 = *(const float4*)src0;
  float4 pr1 = *(const float4*)(src0 + 4096);

  for (int kk = 0; kk < 32; ++kk) {
    __syncthreads();  // prior iter's LDS reads complete
    {
      v4u d;
      d.x = (unsigned)f2bf_rn(pr0.x) | ((unsigned)f2bf_rn(pr1.x) << 16);
      d.y = (unsigned)f2bf_rn(pr0.y) | ((unsigned)f2bf_rn(pr1.y) << 16);
      d.z = (unsigned)f2bf_rn(pr0.z) | ((unsigned)f2bf_rn(pr1.z) << 16);
      d.w = (unsigned)f2bf_rn(pr0.w) | ((unsigned)f2bf_rn(pr1.w) << 16);
      *(v4u*)&ldsB[kp * 68 + 4 * tq] = d;
    }
    __syncthreads();  // tile ready
    {  // prefetch next tile (clamped redundant reload on last iter; L2-hot)
      const int kn = (kk < 31) ? kk + 1 : 31;
      const float* s = src0 + (size_t)kn * 32 * 4096;
      pr0 = *(const float4*)s;
      pr1 = *(const float4*)(s + 4096);
    }
    // B fragments from LDS
    union { unsigned u[4]; v8s s; } bf[4];
#pragma unroll
    for (int nf = 0; nf < 4; ++nf)
#pragma unroll
      for (int jj = 0; jj < 4; ++jj)
        bf[nf].u[jj] = ldsB[(quad * 4 + jj) * 68 + nf * 16 + l16];
    // A fragments direct from global (L2)
    const int kb = (ks * 1024 + kk * 32) * 2;
    v8s af[6];
#pragma unroll
    for (int t = 0; t < 6; ++t)
      if (t < nmt) af[t] = *(const v8s*)((const char*)A + (aoff[t] + kb));
#pragma unroll
    for (int t = 0; t < 6; ++t)
      if (t < nmt)
#pragma unroll
        for (int nf = 0; nf < 4; ++nf)
          acc[t][nf] = __builtin_amdgcn_mfma_f32_16x16x32_bf16(af[t], bf[nf].s, acc[t][nf], 0, 0, 0);
  }

  // ---- fused epilogue: contract over this block's v, atomic-accumulate ----
  const float A01 = 0.011048543f;     // 1/sqrt(2*64*64)
  const float A01IS3 = 0.0063793777f; // A01 / sqrt(3)
  const float A2C = 0.011048543f;     // (1/64)*(1/sqrt(2))
  float* oa = out_acc + (size_t)(bid & (NSLOT - 1)) * OUTN;

  if (slice < 2) {
#pragma unroll
    for (int t = 0; t < 2; ++t)
#pragma unroll
      for (int nf = 0; nf < 4; ++nf)
#pragma unroll
        for (int r = 0; r < 4; ++r) {
          const int b = 16 * (wav + 4 * t) + quad * 4 + r;
          const int w = nf * 16 + l16;
          const float a = acc[t][nf][r];
          if (slice == 0) {
            atomicAdd(oa + b * 448 + w, A01 * wS[b] * a);
          } else {
            atomicAdd(oa + b * 448 + 64 + w * 3 + 0, A01 * wV[b][0] * a);
            atomicAdd(oa + b * 448 + 64 + w * 3 + 1, A01 * wV[b][1] * a);
            atomicAdd(oa + b * 448 + 64 + w * 3 + 2, A01 * wV[b][2] * a);
          }
        }
  } else {
#pragma unroll
    for (int tt = 0; tt < 2; ++tt)
#pragma unroll
      for (int nf = 0; nf < 4; ++nf)
#pragma unroll
        for (int r = 0; r < 4; ++r) {
          const int b = 16 * (wav + 4 * tt) + quad * 4 + r;
          const int w = nf * 16 + l16;
          const float a0 = acc[tt][nf][r];
          const float a1 = acc[2 + tt][nf][r];
          const float a2 = acc[4 + tt][nf][r];
          if (slice == 2) {  // t2[b,w,i] += s2 * acc_i
            const float s2v = A01 * wS[b];
            atomicAdd(oa + b * 448 + 64 + w * 3 + 0, s2v * a0);
            atomicAdd(oa + b * 448 + 64 + w * 3 + 1, s2v * a1);
            atomicAdd(oa + b * 448 + 64 + w * 3 + 2, s2v * a2);
          } else if (slice == 3) {  // t3[b,w] += sum_i v2_i * acc_i
            const float val = wV[b][0] * a0 + wV[b][1] * a1 + wV[b][2] * a2;
            atomicAdd(oa + b * 448 + w, A01IS3 * val);
          } else {  // t4: out2[b,w,k] += eps contraction
            atomicAdd(oa + b * 448 + 256 + w * 3 + 0, A2C * (wV[b][2] * a1 - wV[b][1] * a2));
            atomicAdd(oa + b * 448 + 256 + w * 3 + 1, A2C * (wV[b][0] * a2 - wV[b][2] * a0));
            atomicAdd(oa + b * 448 + 256 + w * 3 + 2, A2C * (wV[b][1] * a0 - wV[b][0] * a1));
          }
        }
  }
}

// ---------------- finish: sum accumulator slots ----------------
__global__ __launch_bounds__(256) void k_finish(const float* __restrict__ acc, float* __restrict__ out)
{
  const int i = blockIdx.x * 256 + threadIdx.x;
  float s = 0.f;
#pragma unroll
  for (int k = 0; k < NSLOT; ++k) s += acc[k * OUTN + i];
  out[i] = s;
}

extern "C" void kernel_launch(void* const* d_in, const int* in_sizes, int n_in,
                              void* d_out, int out_size, void* d_ws, size_t ws_size,
                              hipStream_t stream)
{
  const float* emb = (const float*)d_in[0];
  const float* x1  = (const float*)d_in[1];
  const float* x2  = (const float*)d_in[2];
  const float* W0  = (const float*)d_in[3];
  const float* W1  = (const float*)d_in[4];
  const float* W2  = (const float*)d_in[5];
  const float* P0  = (const float*)d_in[6];
  const float* P1  = (const float*)d_in[7];
  const float* P2  = (const float*)d_in[8];
  const float* P3  = (const float*)d_in[9];
  const float* P4  = (const float*)d_in[10];
  float* out = (float*)d_out;
  char* ws = (char*)d_ws;

  float* hsT  = (float*)ws;                                   // 32 KB
  float* act1 = (float*)(ws + 32768);                         // 128 KB
  float* act2 = (float*)(ws + 163840);                        // 128 KB
  unsigned short* A1 = (unsigned short*)(ws + 294912);        // 1 MB
  unsigned short* A2 = (unsigned short*)(ws + 1343488);       // 3 MB
  float* out_acc = (float*)(ws + 4489216);                    // 8 * 229 KB

  hipMemsetAsync(out_acc, 0, (size_t)NSLOT * OUTN * 4, stream);
  k_mlp1<<<128, 256, 0, stream>>>(emb, W0, act1);
  k_mlp2<<<128, 256, 0, stream>>>(act1, W1, act2);
  k_mlp3<<<32, 256, 0, stream>>>(act2, W2, hsT);
  k_prepA<<<512, 256, 0, stream>>>(x1, hsT, A1, A2);
  gemm_k<<<1280, 256, 0, stream>>>(P0, P1, P2, P3, P4, A1, A2, x2, out_acc);
  k_finish<<<224, 256, 0, stream>>>(out_acc, out);
}